// Round 5
// baseline (207.905 us; speedup 1.0000x reference)
//
#include <hip/hip_runtime.h>
#include <hip/hip_bf16.h>

typedef short short8 __attribute__((ext_vector_type(8)));
typedef float f32x4 __attribute__((ext_vector_type(4)));
typedef unsigned short u16;
typedef u16 u16x4 __attribute__((ext_vector_type(4)));
typedef u16 u16x8 __attribute__((ext_vector_type(8)));

static constexpr float kAlpha = 0.2f;

static __device__ inline u16 f2bf(float f) {
  __hip_bfloat16 h = __float2bfloat16(f);
  return *reinterpret_cast<u16*>(&h);
}
static __device__ inline float bf2f(u16 v) {
  unsigned int u = ((unsigned int)v) << 16;
  return __uint_as_float(u);
}

// ---------------- K1: hbT[b][o][n] = (X @ W)[b][n][o]  (bf16) ----------------
__global__ __launch_bounds__(256) void k1_hW(const float* __restrict__ X,
                                             const float* __restrict__ W,
                                             u16* __restrict__ hbT) {
  int row0 = blockIdx.x * 8;  // global row index over b*4096+n
  int o = threadIdx.x & 127;
  int g = threadIdx.x >> 7;   // 0..1
  __shared__ float Xs[8][128];
#pragma unroll
  for (int s = 0; s < 4; ++s) {
    int idx = threadIdx.x + s * 256;
    Xs[idx >> 7][idx & 127] = X[(size_t)row0 * 128 + idx];
  }
  __syncthreads();
  float acc[4] = {0.f, 0.f, 0.f, 0.f};
  for (int k = 0; k < 128; ++k) {
    float w = W[k * 128 + o];
#pragma unroll
    for (int s = 0; s < 4; ++s) acc[s] += Xs[g + 2 * s][k] * w;
  }
  int b = row0 >> 12;
  int n0 = row0 & 4095;
#pragma unroll
  for (int s = 0; s < 4; ++s)
    hbT[((size_t)b * 128 + o) * 4096 + n0 + g + 2 * s] = f2bf(acc[s]);
}

// ---------------- K1b: f1[b][n] = h.a1, f2[b][n] = h.a2 ----------------
__global__ __launch_bounds__(256) void k1b_f(const u16* __restrict__ hbT,
                                             const float* __restrict__ a1,
                                             const float* __restrict__ a2,
                                             float* __restrict__ f1,
                                             float* __restrict__ f2) {
  int idx = blockIdx.x * 256 + threadIdx.x;  // b*4096+n
  int b = idx >> 12;
  int n = idx & 4095;
  const u16* base = hbT + (size_t)b * 128 * 4096 + n;
  float s1 = 0.f, s2 = 0.f;
  for (int o = 0; o < 128; ++o) {
    float h = bf2f(base[(size_t)o * 4096]);
    s1 += h * a1[o];
    s2 += h * a2[o];
  }
  f1[idx] = s1;
  f2[idx] = s2;
}

// ------- K2_b: P~ = exp(adj*lrelu(f1+f2)) bf16 + partial column sums -------
// One batch. grid = 16jt * 32ic = 512 blocks x 256 thr.
__global__ __launch_bounds__(256) void k2p(const float* __restrict__ adjb,
                                           const float* __restrict__ f1b,
                                           const float* __restrict__ f2b,
                                           u16* __restrict__ ptil,
                                           float* __restrict__ dpart) {
  int bid = blockIdx.x;
  int ic = bid & 31;
  int jt = bid >> 5;  // 0..15
  int t = threadIdx.x;
  int c = t & 63, r = t >> 6;
  int j = jt * 256 + c * 4;
  f32x4 f2v = *reinterpret_cast<const f32x4*>(&f2b[j]);
  int row0 = ic * 128 + r;
  f32x4 sum = (f32x4){0.f, 0.f, 0.f, 0.f};
#pragma unroll 4
  for (int s = 0; s < 32; ++s) {
    int row = row0 + 4 * s;
    f32x4 a = *reinterpret_cast<const f32x4*>(&adjb[(size_t)row * 4096 + j]);
    float f1r = f1b[row];
    u16x4 pv;
#pragma unroll
    for (int k = 0; k < 4; ++k) {
      float e = f1r + f2v[k];
      e = e >= 0.f ? e : kAlpha * e;
      float p = __expf(a[k] * e);
      sum[k] += p;
      pv[k] = f2bf(p);
    }
    *reinterpret_cast<u16x4*>(&ptil[(size_t)row * 4096 + j]) = pv;
  }
  __shared__ f32x4 red[256];
  red[t] = sum;
  __syncthreads();
  if (t < 64) {
    f32x4 tt = red[t] + red[t + 64] + red[t + 128] + red[t + 192];
    *reinterpret_cast<f32x4*>(&dpart[(size_t)ic * 4096 + j]) = tt;
  }
}

// -------- K2b_b: rd=1/colsum; hs[o][j] = hbT_b[o][j] * rd[j] (bf16) --------
__global__ __launch_bounds__(256) void k2bs(const float* __restrict__ dpart,
                                            const u16* __restrict__ hbTb,
                                            u16* __restrict__ hs) {
  int j = blockIdx.x * 256 + threadIdx.x;  // 0..4095
  float s = 0.f;
#pragma unroll
  for (int ic = 0; ic < 32; ++ic) s += dpart[(size_t)ic * 4096 + j];
  float rd = 1.0f / s;
#pragma unroll 4
  for (int o = 0; o < 128; ++o) {
    hs[(size_t)o * 4096 + j] = f2bf(bf2f(hbTb[(size_t)o * 4096 + j]) * rd);
  }
}

// ------- K3_b: parts[q] = P~[:, q-range] @ hs[:, q-range]^T  (MFMA) -------
// grid 256 = 64 row-tiles x 4 j-quarters, 512 thr = 8 waves.
// A-fragments loaded DIRECT global->VGPR from L3-hot ptil (no A-LDS, no exp).
// B (hs) double-buffered in LDS. lgkmcnt-only barriers (loads stay in flight).
#define LROW 72
#define BARRIER()                                      \
  {                                                    \
    asm volatile("s_waitcnt lgkmcnt(0)" ::: "memory"); \
    __builtin_amdgcn_s_barrier();                      \
  }
__global__ __launch_bounds__(512) void k3p(const u16* __restrict__ ptil,
                                           const u16* __restrict__ hs,
                                           float* __restrict__ parts) {
  int bid = blockIdx.x;
  int i0 = (bid & 63) * 64;
  int q = bid >> 6;  // j-quarter
  int jbase = q * 1024;
  int t = threadIdx.x;
  int lane = t & 63;
  int w = t >> 6;

  __shared__ u16 Bs[2][128 * LROW];

  // B staging map: thread covers o=bo, 16 cols starting bc0
  int bo = t >> 2;         // 0..127
  int bc0 = (t & 3) * 16;  // 0..48

  f32x4 acc[4];
#pragma unroll
  for (int n = 0; n < 4; ++n) acc[n] = (f32x4){0.f, 0.f, 0.f, 0.f};

  int rg = w & 3;   // row group (16 rows)
  int ch = w >> 2;  // column half of o (64)

  // A-frag row for this lane (constant across tiles)
  const u16* arow = ptil + (size_t)(i0 + 16 * rg + (lane & 15)) * 4096 + (lane >> 4) * 8;

  // 4 named prefetch register sets (static indexing only)
  u16x8 afA0, afA1, afB0, afB1, afC0, afC1, afD0, afD1;
  u16x8 rbA0, rbA1, rbB0, rbB1, rbC0, rbC1, rbD0, rbD1;

#define PREFETCH(S, J0)                                                     \
  {                                                                         \
    int jj = (J0) & 4095; /* tail prefetches wrap, values unused */         \
    af##S##0 = *reinterpret_cast<const u16x8*>(arow + jj);                  \
    af##S##1 = *reinterpret_cast<const u16x8*>(arow + jj + 32);             \
    const u16x8* bp =                                                       \
        reinterpret_cast<const u16x8*>(hs + (size_t)bo * 4096 + jj + bc0);  \
    rb##S##0 = bp[0];                                                       \
    rb##S##1 = bp[1];                                                       \
  }

#define STORE(S, BUF)                                                       \
  {                                                                         \
    *reinterpret_cast<u16x8*>(&Bs[BUF][bo * LROW + bc0]) = rb##S##0;        \
    *reinterpret_cast<u16x8*>(&Bs[BUF][bo * LROW + bc0 + 8]) = rb##S##1;    \
  }

#define DOMFMA(BUF, S)                                                               \
  {                                                                                  \
    _Pragma("unroll") for (int n = 0; n < 4; ++n) {                                  \
      short8 bf = *reinterpret_cast<const short8*>(                                  \
          &Bs[BUF][(64 * ch + n * 16 + (lane & 15)) * LROW + (lane >> 4) * 8]);      \
      acc[n] = __builtin_amdgcn_mfma_f32_16x16x32_bf16(                              \
          *reinterpret_cast<const short8*>(&af##S##0), bf, acc[n], 0, 0, 0);         \
    }                                                                                \
    _Pragma("unroll") for (int n = 0; n < 4; ++n) {                                  \
      short8 bf = *reinterpret_cast<const short8*>(                                  \
          &Bs[BUF][(64 * ch + n * 16 + (lane & 15)) * LROW + 32 + (lane >> 4) * 8]); \
      acc[n] = __builtin_amdgcn_mfma_f32_16x16x32_bf16(                              \
          *reinterpret_cast<const short8*>(&af##S##1), bf, acc[n], 0, 0, 0);         \
    }                                                                                \
  }

  // Prologue: fill the 4-deep pipeline.
  PREFETCH(A, jbase);
  PREFETCH(B, jbase + 64);
  PREFETCH(C, jbase + 128);
  PREFETCH(D, jbase + 192);

  for (int j0 = jbase; j0 < jbase + 1024; j0 += 256) {
    STORE(A, 0);
    BARRIER();
    DOMFMA(0, A);
    PREFETCH(A, j0 + 256);
    STORE(B, 1);
    BARRIER();
    DOMFMA(1, B);
    PREFETCH(B, j0 + 320);
    STORE(C, 0);
    BARRIER();
    DOMFMA(0, C);
    PREFETCH(C, j0 + 384);
    STORE(D, 1);
    BARRIER();
    DOMFMA(1, D);
    PREFETCH(D, j0 + 448);
  }

  // ---- write f32 partials: parts[q][i][o] ----
  int colbase = ch * 64 + (lane & 15);
  int rowbase = i0 + rg * 16 + (lane >> 4) * 4;
  float* pq = parts + (size_t)q * 4096 * 128;
#pragma unroll
  for (int n = 0; n < 4; ++n) {
    int o = colbase + n * 16;
#pragma unroll
    for (int qq = 0; qq < 4; ++qq) {
      pq[(size_t)(rowbase + qq) * 128 + o] = acc[n][qq];
    }
  }
}

// ------- K4_b: out[b] = sum_q parts[q] + bias + input[b] -------
// grid 512 x 256, one f32x4 per thread (4096*128 = 131072 f32x4).
__global__ __launch_bounds__(256) void k4r(const float* __restrict__ parts,
                                           const float* __restrict__ bias,
                                           const float* __restrict__ inputb,
                                           float* __restrict__ outb) {
  size_t v = (size_t)blockIdx.x * 256 + threadIdx.x;  // f32x4 index
  size_t e = v * 4;
  f32x4 s = *reinterpret_cast<const f32x4*>(&parts[e]);
  s += *reinterpret_cast<const f32x4*>(&parts[e + 524288]);
  s += *reinterpret_cast<const f32x4*>(&parts[e + 2 * 524288]);
  s += *reinterpret_cast<const f32x4*>(&parts[e + 3 * 524288]);
  s += *reinterpret_cast<const f32x4*>(&bias[e]);
  s += *reinterpret_cast<const f32x4*>(&inputb[e]);
  *reinterpret_cast<f32x4*>(&outb[e]) = s;
}

extern "C" void kernel_launch(void* const* d_in, const int* in_sizes, int n_in,
                              void* d_out, int out_size, void* d_ws, size_t ws_size,
                              hipStream_t stream) {
  const float* input = (const float*)d_in[0];
  const float* adj = (const float*)d_in[1];
  const float* W = (const float*)d_in[2];
  const float* a1 = (const float*)d_in[3];
  const float* a2 = (const float*)d_in[4];
  const float* bias = (const float*)d_in[5];
  float* out = (float*)d_out;

  char* ws = (char*)d_ws;
  u16* hbT = (u16*)(ws);                   // 4,194,304 B
  float* f1 = (float*)(ws + 4194304);      // 65,536 B
  float* f2 = (float*)(ws + 4259840);      // 65,536 B
  float* dpart = (float*)(ws + 4325376);   // 32*4096*4 = 524,288 B
  u16* hs = (u16*)(ws + 4849664);          // 128*4096*2 = 1,048,576 B
  u16* ptil = (u16*)(ws + 5898240);        // 4096*4096*2 = 33,554,432 B
  float* parts = (float*)(ws + 39452672);  // 4*4096*128*4 = 8,388,608 B

  k1_hW<<<2048, 256, 0, stream>>>(input, W, hbT);
  k1b_f<<<64, 256, 0, stream>>>(hbT, a1, a2, f1, f2);

  for (int b = 0; b < 4; ++b) {
    const float* adjb = adj + (size_t)b * 4096 * 4096;
    const float* f1b = f1 + b * 4096;
    const float* f2b = f2 + b * 4096;
    const u16* hbTb = hbT + (size_t)b * 128 * 4096;
    const float* inputb = input + (size_t)b * 4096 * 128;
    float* outb = out + (size_t)b * 4096 * 128;

    k2p<<<512, 256, 0, stream>>>(adjb, f1b, f2b, ptil, dpart);
    k2bs<<<16, 256, 0, stream>>>(dpart, hbTb, hs);
    k3p<<<256, 512, 0, stream>>>(ptil, hs, parts);
    k4r<<<512, 256, 0, stream>>>(parts, bias, inputb, outb);
  }
}